// Round 1
// baseline (34156.366 us; speedup 1.0000x reference)
//
#include <hip/hip_runtime.h>
#include <math.h>

#define NBLK 256
#define NTHR 256
#define BB 64
#define SS 128
#define HH 512
#define EE 256
#define VV 32000
#define TT 32
#define EXTW 32128   // VV + SS
#define KX 1280      // 2H + E

typedef unsigned int u32;

// ---------------- grid-wide barrier (manual, device scope) ----------------
__device__ __forceinline__ void gsync(u32* cnt, u32* gen) {
  __syncthreads();
  if (threadIdx.x == 0) {
    u32 g = __hip_atomic_load(gen, __ATOMIC_RELAXED, __HIP_MEMORY_SCOPE_AGENT);
    u32 prev = __hip_atomic_fetch_add(cnt, 1u, __ATOMIC_ACQ_REL, __HIP_MEMORY_SCOPE_AGENT);
    if (prev == (u32)(NBLK - 1)) {
      __hip_atomic_store(cnt, 0u, __ATOMIC_RELAXED, __HIP_MEMORY_SCOPE_AGENT);
      __hip_atomic_store(gen, g + 1u, __ATOMIC_RELEASE, __HIP_MEMORY_SCOPE_AGENT);
    } else {
      while (__hip_atomic_load(gen, __ATOMIC_ACQUIRE, __HIP_MEMORY_SCOPE_AGENT) == g) {
        __builtin_amdgcn_s_sleep(2);
      }
    }
  }
  __syncthreads();
}

__device__ __forceinline__ float wave_red_sum(float v) {
#pragma unroll
  for (int o = 1; o < 64; o <<= 1) v += __shfl_xor(v, o, 64);
  return v;
}
__device__ __forceinline__ float wave_red_max(float v) {
#pragma unroll
  for (int o = 1; o < 64; o <<= 1) v = fmaxf(v, __shfl_xor(v, o, 64));
  return v;
}

// ---------------- medium GEMM: out[64 x 64-tile] = x[64xK] @ W[N x K]^T ----------------
// tile 64x64, micro 4x4, K chunked by 32.  LDS: A[32][68], B[32][68]
__device__ void gemm_m(const float* __restrict__ x, int ldx,
                       const float* __restrict__ W, int ldw,
                       int n0, int k0, int klen,
                       float* __restrict__ out, int ldo, float* lds) {
  const int tid = threadIdx.x;
  const int tm = tid >> 4, tn = tid & 15;
  float* A  = lds;          // [32][68]
  float* Bm = lds + 2176;   // [32][68]
  float acc[4][4];
#pragma unroll
  for (int i = 0; i < 4; ++i)
#pragma unroll
    for (int j = 0; j < 4; ++j) acc[i][j] = 0.f;
  const int ab = tid >> 2, ak = tid & 3;
  const int bk = tid & 7, bn = tid >> 3;
  for (int kk = k0; kk < k0 + klen; kk += 32) {
    __syncthreads();
#pragma unroll
    for (int h = 0; h < 2; ++h) {
      int kq = ak + h * 4;
      const float4 v = *(const float4*)(x + (size_t)ab * ldx + kk + kq * 4);
      A[(kq * 4 + 0) * 68 + ab] = v.x;
      A[(kq * 4 + 1) * 68 + ab] = v.y;
      A[(kq * 4 + 2) * 68 + ab] = v.z;
      A[(kq * 4 + 3) * 68 + ab] = v.w;
    }
#pragma unroll
    for (int h = 0; h < 2; ++h) {
      int nn = bn + h * 32;
      const float4 v = *(const float4*)(W + (size_t)(n0 + nn) * ldw + kk + bk * 4);
      Bm[(bk * 4 + 0) * 68 + nn] = v.x;
      Bm[(bk * 4 + 1) * 68 + nn] = v.y;
      Bm[(bk * 4 + 2) * 68 + nn] = v.z;
      Bm[(bk * 4 + 3) * 68 + nn] = v.w;
    }
    __syncthreads();
    for (int k = 0; k < 32; ++k) {
      const float4 a = *(const float4*)(A + k * 68 + tm * 4);
      const float4 b = *(const float4*)(Bm + k * 68 + tn * 4);
      float av[4] = {a.x, a.y, a.z, a.w};
      float bv[4] = {b.x, b.y, b.z, b.w};
#pragma unroll
      for (int i = 0; i < 4; ++i)
#pragma unroll
        for (int j = 0; j < 4; ++j) acc[i][j] = fmaf(av[i], bv[j], acc[i][j]);
    }
  }
#pragma unroll
  for (int i = 0; i < 4; ++i) {
    float4 v; v.x = acc[i][0]; v.y = acc[i][1]; v.z = acc[i][2]; v.w = acc[i][3];
    *(float4*)(out + (size_t)(tm * 4 + i) * ldo + n0 + tn * 4) = v;
  }
}

// ---------------- big GEMM (gen): tile 64x256, micro 8x8, W is out_w [VV][512] ----------------
__device__ void gemm_g(const float* __restrict__ x, const float* __restrict__ W,
                       int n0, int k0, int klen, float* __restrict__ out, float* lds) {
  const int tid = threadIdx.x;
  const int tm = tid >> 5, tn = tid & 31;
  float* A  = lds;          // [32][68]
  float* Bm = lds + 2176;   // [32][260]
  float acc[8][8];
#pragma unroll
  for (int i = 0; i < 8; ++i)
#pragma unroll
    for (int j = 0; j < 8; ++j) acc[i][j] = 0.f;
  const int ab = tid >> 2, ak = tid & 3;
  const int bk = tid & 7, bn = tid >> 3;
  for (int kk = k0; kk < k0 + klen; kk += 32) {
    __syncthreads();
#pragma unroll
    for (int h = 0; h < 2; ++h) {
      int kq = ak + h * 4;
      const float4 v = *(const float4*)(x + (size_t)ab * HH + kk + kq * 4);
      A[(kq * 4 + 0) * 68 + ab] = v.x;
      A[(kq * 4 + 1) * 68 + ab] = v.y;
      A[(kq * 4 + 2) * 68 + ab] = v.z;
      A[(kq * 4 + 3) * 68 + ab] = v.w;
    }
#pragma unroll
    for (int h = 0; h < 8; ++h) {
      int nn = bn + h * 32;
      const float4 v = *(const float4*)(W + (size_t)(n0 + nn) * HH + kk + bk * 4);
      Bm[(bk * 4 + 0) * 260 + nn] = v.x;
      Bm[(bk * 4 + 1) * 260 + nn] = v.y;
      Bm[(bk * 4 + 2) * 260 + nn] = v.z;
      Bm[(bk * 4 + 3) * 260 + nn] = v.w;
    }
    __syncthreads();
    for (int k = 0; k < 32; ++k) {
      const float4 a0 = *(const float4*)(A + k * 68 + tm * 8);
      const float4 a1 = *(const float4*)(A + k * 68 + tm * 8 + 4);
      const float4 b0 = *(const float4*)(Bm + k * 260 + tn * 4);
      const float4 b1 = *(const float4*)(Bm + k * 260 + 128 + tn * 4);
      float av[8] = {a0.x, a0.y, a0.z, a0.w, a1.x, a1.y, a1.z, a1.w};
      float bv[8] = {b0.x, b0.y, b0.z, b0.w, b1.x, b1.y, b1.z, b1.w};
#pragma unroll
      for (int i = 0; i < 8; ++i)
#pragma unroll
        for (int j = 0; j < 8; ++j) acc[i][j] = fmaf(av[i], bv[j], acc[i][j]);
    }
  }
#pragma unroll
  for (int i = 0; i < 8; ++i) {
    float4 v0; v0.x = acc[i][0]; v0.y = acc[i][1]; v0.z = acc[i][2]; v0.w = acc[i][3];
    float4 v1; v1.x = acc[i][4]; v1.y = acc[i][5]; v1.z = acc[i][6]; v1.w = acc[i][7];
    *(float4*)(out + (size_t)(tm * 8 + i) * VV + n0 + tn * 4) = v0;
    *(float4*)(out + (size_t)(tm * 8 + i) * VV + n0 + 128 + tn * 4) = v1;
  }
}

// ---------------- attention for one batch row (scores -> softmax -> context) ----------------
__device__ void phaseA(int b, const float* __restrict__ enc,
                       const float* __restrict__ thp, const float* __restrict__ attnb,
                       float* __restrict__ rnn, float* lds) {
  const int tid = threadIdx.x;
  float* thl = lds;        // 512
  float* sc  = lds + 512;  // 128
  for (int i = tid; i < HH; i += NTHR)
    thl[i] = thp[(size_t)b * HH + i] + thp[32768 + (size_t)b * HH + i] + attnb[i];
  __syncthreads();
  const int wid = tid >> 6, lane = tid & 63;
  for (int s = wid; s < SS; s += 4) {
    const float* er = enc + ((size_t)b * SS + s) * HH;
    float a = 0.f;
#pragma unroll
    for (int kk = 0; kk < 8; ++kk) a += er[kk * 64 + lane] * thl[kk * 64 + lane];
    a = wave_red_sum(a);
    if (lane == 0) sc[s] = a;
  }
  __syncthreads();
  if (wid == 0) {
    float v0 = sc[lane], v1 = sc[64 + lane];
    float m = wave_red_max(fmaxf(v0, v1));
    float e0 = expf(v0 - m), e1 = expf(v1 - m);
    float sum = wave_red_sum(e0 + e1);
    sc[lane] = e0 / sum;
    sc[64 + lane] = e1 / sum;
  }
  __syncthreads();
  for (int h = tid; h < HH; h += NTHR) {
    float c = 0.f;
    for (int s = 0; s < SS; ++s) c += sc[s] * enc[((size_t)b * SS + s) * HH + h];
    rnn[(size_t)b * KX + h] = c;
  }
}

// ---------------- copy scores + scatter (deterministic, JAX ascending-index order) ----------------
__device__ void phaseE(int b, const float* __restrict__ enc,
                       const float* __restrict__ th2p, const float* __restrict__ copyb,
                       const int* __restrict__ inp, float* __restrict__ cssg,
                       float* __restrict__ cd, float* lds) {
  const int tid = threadIdx.x;
  float* thl = lds;             // 512
  float* sc  = lds + 512;       // 128
  int*   il  = (int*)(lds + 640); // 128
  for (int i = tid; i < HH; i += NTHR)
    thl[i] = th2p[(size_t)b * HH + i] + th2p[32768 + (size_t)b * HH + i] + copyb[i];
  if (tid < SS) il[tid] = inp[b * SS + tid];
  __syncthreads();
  const int wid = tid >> 6, lane = tid & 63;
  for (int s = wid; s < SS; s += 4) {
    const float* er = enc + ((size_t)b * SS + s) * HH;
    float a = 0.f;
#pragma unroll
    for (int kk = 0; kk < 8; ++kk) a += er[kk * 64 + lane] * thl[kk * 64 + lane];
    a = wave_red_sum(a);
    if (lane == 0) sc[s] = a;
  }
  __syncthreads();
  if (tid < SS) {
    cssg[b * SS + tid] = sc[tid];
    int tok = il[tid];
    if (tok != 0) {
      bool first = true;
      for (int s2 = 0; s2 < tid; ++s2)
        if (il[s2] == tok) { first = false; break; }
      if (first) {
        float v = 0.f;
        for (int s2 = tid; s2 < SS; ++s2)
          if (il[s2] == tok) v += sc[s2];
        cd[(size_t)b * VV + tok] = v;   // overwrite each step; untouched tokens stay -1e6
      }
    }
  }
}

// ---------------- per-(row,slice) softmax partials: max, sum, argmax of (e1+e2) ----------------
__device__ void phaseF(int blk, const float* __restrict__ genp, const float* __restrict__ outbv,
                       const float* __restrict__ cd,
                       float* pm, float* pz, float* pbv, int* pbi, float* lds) {
  const int tid = threadIdx.x;
  const int b = blk >> 2, sl = blk & 3;
  const int j0 = sl * 8000, jend = j0 + 8000;
  const float* g0 = genp + (size_t)b * VV;
  const float* g1 = g0 + 2048000;
  const float* g2 = g1 + 2048000;
  const float* g3 = g2 + 2048000;
  const float* cdr = cd + (size_t)b * VV;
  float m = -3.4e38f;
  for (int j = j0 + tid; j < jend; j += NTHR) {
    float l1 = (j == 0) ? -1e6f : (g0[j] + g1[j] + g2[j] + g3[j] + outbv[j]);
    float l2 = cdr[j];
    m = fmaxf(m, fmaxf(l1, l2));
  }
  float* red = lds;
  red[tid] = m;
  __syncthreads();
  for (int s = 128; s > 0; s >>= 1) {
    if (tid < s) red[tid] = fmaxf(red[tid], red[tid + s]);
    __syncthreads();
  }
  const float smax = red[0];
  __syncthreads();
  float z = 0.f, bv = -1.f;
  int bi = 0x7fffffff;
  for (int j = j0 + tid; j < jend; j += NTHR) {
    float l1 = (j == 0) ? -1e6f : (g0[j] + g1[j] + g2[j] + g3[j] + outbv[j]);
    float l2 = cdr[j];
    float v = expf(l1 - smax) + expf(l2 - smax);
    z += v;
    if (v > bv) { bv = v; bi = j; }
  }
  float* rv = lds + 256;
  int* ri = (int*)(lds + 512);
  red[tid] = z; rv[tid] = bv; ri[tid] = bi;
  __syncthreads();
  for (int s = 128; s > 0; s >>= 1) {
    if (tid < s) {
      red[tid] += red[tid + s];
      float v2 = rv[tid + s]; int i2 = ri[tid + s];
      if (v2 > rv[tid] || (v2 == rv[tid] && i2 < ri[tid])) { rv[tid] = v2; ri[tid] = i2; }
    }
    __syncthreads();
  }
  if (tid == 0) {
    pm[b * 4 + sl] = smax;
    pz[b * 4 + sl] = red[0];
    pbv[b * 4 + sl] = rv[0];
    pbi[b * 4 + sl] = ri[0];
  }
}

// ---------------- finalize: logp write + argmax + selective-read + emb + NEXT attention ----------------
__device__ void phaseG(int blk, int step,
                       const float* __restrict__ genp, const float* __restrict__ outbv,
                       const float* __restrict__ cd,
                       const float* pm, const float* pz, const float* pbv, const int* pbi,
                       const float* __restrict__ enc, const int* __restrict__ inp,
                       const float* __restrict__ cssg, const float* __restrict__ embw,
                       const float* __restrict__ thp, const float* __restrict__ attnb,
                       float* __restrict__ rnn, float* __restrict__ out, float* lds) {
  const int tid = threadIdx.x;
  const int r = blk & 63;
  float M = fmaxf(fmaxf(pm[r * 4 + 0], pm[r * 4 + 1]), fmaxf(pm[r * 4 + 2], pm[r * 4 + 3]));
  float Z = 0.f;
#pragma unroll
  for (int sl = 0; sl < 4; ++sl) Z += pz[r * 4 + sl] * expf(pm[r * 4 + sl] - M);

  if (blk < 64) {
    // argmax across slices (ascending slice order => first-index tie-break)
    float bv = -1.f; int bi = 0;
#pragma unroll
    for (int sl = 0; sl < 4; ++sl) {
      float v = pbv[r * 4 + sl] * expf(pm[r * 4 + sl] - M);
      if (v > bv) { bv = v; bi = pbi[r * 4 + sl]; }
    }
    if (tid == 0) out[(size_t)BB * TT * EXTW + (size_t)r * TT + step] = (float)bi;
    float* ssw = lds;        // 128
    float* red = lds + 128;  // 64+
    if (tid < SS) {
      int tok = inp[r * SS + tid];
      ssw[tid] = (tok == bi) ? cssg[r * SS + tid] : 0.f;
    }
    __syncthreads();
    if (tid < 64) red[tid] = fabsf(ssw[tid]) + fabsf(ssw[tid + 64]);
    __syncthreads();
    for (int s = 32; s > 0; s >>= 1) {
      if (tid < s) red[tid] += red[tid + s];
      __syncthreads();
    }
    float norm = fmaxf(red[0], 1e-12f);
    __syncthreads();
    if (tid < SS) ssw[tid] = ssw[tid] / norm;
    __syncthreads();
    for (int h = tid; h < HH; h += NTHR) {
      float sv = 0.f;
      for (int s = 0; s < SS; ++s) sv += ssw[s] * enc[((size_t)r * SS + s) * HH + h];
      rnn[(size_t)r * KX + HH + h] = sv;
    }
    int ic = (bi > VV) ? 3 : bi;
    if (ic > VV - 1) ic = VV - 1;
    if (tid < EE) rnn[(size_t)r * KX + 1024 + tid] = embw[(size_t)ic * EE + tid];
  } else if (blk < 128) {
    // attention for the NEXT step (th already updated from h_new this step)
    phaseA(blk - 64, enc, thp, attnb, rnn, lds);
  }

  // logp writes (chunked; busy blocks get smaller chunks)
  const int c = blk >> 6;
  const int j0  = (c == 0) ? 0 : (c == 1) ? 6016 : (c == 2) ? 12032 : 22080;
  const int jend = (c == 0) ? 6016 : (c == 1) ? 12032 : (c == 2) ? 22080 : 32128;
  const float* g0 = genp + (size_t)r * VV;
  const float* g1 = g0 + 2048000;
  const float* g2 = g1 + 2048000;
  const float* g3 = g2 + 2048000;
  const float* cdr = cd + (size_t)r * VV;
  float* orow = out + ((size_t)r * TT + step) * EXTW;
  const float LP_TAIL = logf(1e-10f);
  for (int j = j0 + tid; j < jend; j += NTHR) {
    float lp;
    if (j < VV) {
      float l1 = (j == 0) ? -1e6f : (g0[j] + g1[j] + g2[j] + g3[j] + outbv[j]);
      float l2 = cdr[j];
      float v = expf(l1 - M) + expf(l2 - M);
      lp = logf(v / Z + 1e-10f);
    } else {
      lp = LP_TAIL;
    }
    orow[j] = lp;
  }
}

// ---------------- main persistent kernel ----------------
__global__ __launch_bounds__(NTHR, 1) void copynet(
    const float* __restrict__ enc, const int* __restrict__ inp,
    const float* __restrict__ embw,
    const float* __restrict__ attnw, const float* __restrict__ attnb,
    const float* __restrict__ copyw, const float* __restrict__ copyb,
    const float* __restrict__ wih, const float* __restrict__ whh,
    const float* __restrict__ bih, const float* __restrict__ bhh,
    const float* __restrict__ outw, const float* __restrict__ outbv,
    float* __restrict__ out, u32* __restrict__ wsu) {
  __shared__ float lds[10496];
  u32* cnt = wsu + 0;
  u32* gen = wsu + 1;
  float* ws   = (float*)(wsu) + 64;
  float* hid  = ws;                  // [64][512]
  float* rnn  = hid + 32768;         // [64][1280]  ctx | sel | emb
  float* thp  = rnn + 81920;         // [2][64][512]
  float* th2p = thp + 65536;         // [2][64][512]
  float* gip  = th2p + 65536;        // [8][64][1536]
  float* ghp  = gip + 786432;        // [4][64][1536]
  float* genp = ghp + 393216;        // [4][64][32000]
  float* cd   = genp + 8192000;      // [64][32000]
  float* cssg = cd + 2048000;        // [64][128]
  float* pm   = cssg + 8192;         // [64][4]
  float* pz   = pm + 256;
  float* pbv  = pz + 256;
  int*   pbi  = (int*)(pbv + 256);

  const int blk = blockIdx.x, tid = threadIdx.x;
  const size_t gt = (size_t)blk * NTHR + tid;
  const size_t gs = (size_t)NBLK * NTHR;

  // ---- prologue: init state, copy_dense=-1e6, sos row, sampled[.,0]=1, emb(idx=1), th partials=0
  for (size_t i = gt; i < 32768; i += gs) hid[i] = 0.f;
  for (size_t i = gt; i < 65536; i += gs) { size_t b = i >> 10, k = i & 1023; rnn[b * KX + k] = 0.f; }
  for (size_t i = gt; i < 16384; i += gs) { size_t b = i >> 8, e = i & 255; rnn[b * KX + 1024 + e] = embw[256 + e]; }
  for (size_t i = gt; i < 65536; i += gs) thp[i] = 0.f;
  for (size_t i = gt; i < 2048000; i += gs) cd[i] = -1e6f;
  for (size_t i = gt; i < (size_t)BB * EXTW; i += gs) {
    size_t b = i / EXTW, j = i % EXTW;
    out[b * TT * EXTW + j] = (j == 1) ? 1.f : 0.f;
  }
  for (size_t i = gt; i < 64; i += gs) out[(size_t)BB * TT * EXTW + i * TT] = 1.f;
  gsync(cnt, gen);
  if (blk < 64) phaseA(blk, enc, thp, attnb, rnn, lds);
  gsync(cnt, gen);

  for (int step = 1; step < TT; ++step) {
    // B: GRU input/hidden GEMM partials (deterministic K-split)
    for (int job = blk; job < 288; job += NBLK) {
      if (job < 192) {
        int nt = job % 24, ks = job / 24;
        gemm_m(rnn, KX, wih, KX, nt * 64, ks * 160, 160, gip + (size_t)ks * 98304, 1536, lds);
      } else {
        int t = job - 192; int nt = t % 24, ks = t / 24;
        gemm_m(hid, HH, whh, HH, nt * 64, ks * 128, 128, ghp + (size_t)ks * 98304, 1536, lds);
      }
    }
    gsync(cnt, gen);
    // C: GRU elementwise -> hid (in place)
    {
      int t = blk * NTHR + tid;
      if (t < 32768) {
        int b = t >> 9, g = t & 511;
        float gir = bih[g], giz = bih[512 + g], gin = bih[1024 + g];
#pragma unroll
        for (int ks = 0; ks < 8; ++ks) {
          const float* p = gip + (size_t)ks * 98304 + (size_t)b * 1536;
          gir += p[g]; giz += p[512 + g]; gin += p[1024 + g];
        }
        float ghr = bhh[g], ghz = bhh[512 + g], ghn = bhh[1024 + g];
#pragma unroll
        for (int ks = 0; ks < 4; ++ks) {
          const float* p = ghp + (size_t)ks * 98304 + (size_t)b * 1536;
          ghr += p[g]; ghz += p[512 + g]; ghn += p[1024 + g];
        }
        float rr = 1.f / (1.f + expf(-(gir + ghr)));
        float zz = 1.f / (1.f + expf(-(giz + ghz)));
        float nn = tanhf(gin + rr * ghn);
        hid[t] = (1.f - zz) * nn + zz * hid[t];
      }
    }
    gsync(cnt, gen);
    // D: gen (big), th (next-step attention proj), th2 (copy proj)
    for (int job = blk; job < 532; job += NBLK) {
      if (job < 500) {
        int nt = job % 125, ks = job / 125;
        gemm_g(hid, outw, nt * 256, ks * 128, 128, genp + (size_t)ks * 2048000, lds);
      } else {
        int t = job - 500;
        if (t < 16) {
          int nt = t & 7, ks = t >> 3;
          gemm_m(hid, HH, attnw, HH, nt * 64, ks * 256, 256, thp + (size_t)ks * 32768, HH, lds);
        } else {
          t -= 16; int nt = t & 7, ks = t >> 3;
          gemm_m(hid, HH, copyw, HH, nt * 64, ks * 256, 256, th2p + (size_t)ks * 32768, HH, lds);
        }
      }
    }
    gsync(cnt, gen);
    // E: copy scores + scatter into dense extended-vocab slots
    if (blk < 64) phaseE(blk, enc, th2p, copyb, inp, cssg, cd, lds);
    gsync(cnt, gen);
    // F: softmax partials per (row, slice)
    phaseF(blk, genp, outbv, cd, pm, pz, pbv, pbi, lds);
    gsync(cnt, gen);
    // G: logp + argmax + selective read + emb + next-step attention
    phaseG(blk, step, genp, outbv, cd, pm, pz, pbv, pbi,
           enc, inp, cssg, embw, thp, attnb, rnn, out, lds);
    gsync(cnt, gen);
  }
}

extern "C" void kernel_launch(void* const* d_in, const int* in_sizes, int n_in,
                              void* d_out, int out_size, void* d_ws, size_t ws_size,
                              hipStream_t stream) {
  const float* enc   = (const float*)d_in[0];
  const int*   inp   = (const int*)d_in[1];
  // d_in[2] final_encoder_hidden: unused by the reference
  const float* embw  = (const float*)d_in[3];
  const float* attnw = (const float*)d_in[4];
  const float* attnb = (const float*)d_in[5];
  const float* copyw = (const float*)d_in[6];
  const float* copyb = (const float*)d_in[7];
  const float* wih   = (const float*)d_in[8];
  const float* whh   = (const float*)d_in[9];
  const float* bih   = (const float*)d_in[10];
  const float* bhh   = (const float*)d_in[11];
  const float* outw  = (const float*)d_in[12];
  const float* outb  = (const float*)d_in[13];
  (void)in_sizes; (void)n_in; (void)out_size; (void)ws_size;
  hipMemsetAsync(d_ws, 0, 256, stream);  // grid-barrier counters
  copynet<<<dim3(NBLK), dim3(NTHR), 0, stream>>>(
      enc, inp, embw, attnw, attnb, copyw, copyb,
      wih, whh, bih, bhh, outw, outb,
      (float*)d_out, (u32*)d_ws);
}

// Round 3
// 16781.972 us; speedup vs baseline: 2.0353x; 2.0353x over previous
//
#include <hip/hip_runtime.h>
#include <math.h>

#define NBLK 512
#define NTHR 256
#define BB 64
#define SS 128
#define HH 512
#define EE 256
#define VV 32000
#define TT 32
#define EXTW 32128
#define KX 1280

typedef unsigned int u32;

// ---------------- 2-level grid barrier (device scope) ----------------
__device__ __forceinline__ void gsync(u32* bar) {
  __syncthreads();
  if (threadIdx.x == 0) {
    u32* gcnt = bar + (blockIdx.x & 7) * 16;
    u32 g = __hip_atomic_load(bar + 144, __ATOMIC_RELAXED, __HIP_MEMORY_SCOPE_AGENT);
    bool done = false;
    if (__hip_atomic_fetch_add(gcnt, 1u, __ATOMIC_ACQ_REL, __HIP_MEMORY_SCOPE_AGENT) == 63u) {
      __hip_atomic_store(gcnt, 0u, __ATOMIC_RELAXED, __HIP_MEMORY_SCOPE_AGENT);
      if (__hip_atomic_fetch_add(bar + 128, 1u, __ATOMIC_ACQ_REL, __HIP_MEMORY_SCOPE_AGENT) == 7u) {
        __hip_atomic_store(bar + 128, 0u, __ATOMIC_RELAXED, __HIP_MEMORY_SCOPE_AGENT);
        __hip_atomic_store(bar + 144, g + 1u, __ATOMIC_RELEASE, __HIP_MEMORY_SCOPE_AGENT);
        done = true;
      }
    }
    if (!done) {
      while (__hip_atomic_load(bar + 144, __ATOMIC_ACQUIRE, __HIP_MEMORY_SCOPE_AGENT) == g)
        __builtin_amdgcn_s_sleep(2);
    }
  }
  __syncthreads();
}

__device__ __forceinline__ float rmax32(float v) {
#pragma unroll
  for (int o = 1; o < 32; o <<= 1) v = fmaxf(v, __shfl_xor(v, o));
  return v;
}
__device__ __forceinline__ float rsum32(float v) {
#pragma unroll
  for (int o = 1; o < 32; o <<= 1) v += __shfl_xor(v, o);
  return v;
}

// ---------------- 32x128 tile GEMM, K chunked by 32, reg-prefetch + LDS dbuf ----
// TRANSB: B is W[N][K] row-major (contract over K). else B is [K][N] row-major.
// LDS: Am[2][32][36], Bm[2][32][136]  (11008 floats)
template<bool TRANSB>
__device__ void gemm_t(const float* __restrict__ X, int ldx, int xr0,
                       const float* __restrict__ Bp, int ldb, int n0, int k0, int nch,
                       float* __restrict__ outp, int ldo, int or0, float* lds) {
  const int tid = threadIdx.x;
  const int tm = tid >> 5, tn = tid & 31;
  float* Am = lds;
  float* Bm = lds + 2304;
  float acc[4][4] = {};
  const int ar = tid >> 3, aq = tid & 7;
  const int bn = tid >> 1, bh = tid & 1;
  const int bk = tid >> 3, bq = tid & 7;
  float4 aR; float4 bR[4];
  {
    int kc = k0;
    aR = *(const float4*)(X + (size_t)(xr0 + ar) * ldx + kc + aq * 4);
    if (TRANSB) {
#pragma unroll
      for (int q = 0; q < 4; ++q)
        bR[q] = *(const float4*)(Bp + (size_t)(n0 + bn) * ldb + kc + bh * 16 + q * 4);
    } else {
#pragma unroll
      for (int q = 0; q < 4; ++q)
        bR[q] = *(const float4*)(Bp + (size_t)(kc + bk) * ldb + n0 + bq * 4 + q * 32);
    }
  }
  for (int c = 0; c < nch; ++c) {
    float* A = Am + (c & 1) * 1152;
    float* Bl = Bm + (c & 1) * 4352;
    A[(aq * 4 + 0) * 36 + ar] = aR.x;
    A[(aq * 4 + 1) * 36 + ar] = aR.y;
    A[(aq * 4 + 2) * 36 + ar] = aR.z;
    A[(aq * 4 + 3) * 36 + ar] = aR.w;
    if (TRANSB) {
#pragma unroll
      for (int q = 0; q < 4; ++q) {
        Bl[(bh * 16 + q * 4 + 0) * 136 + bn] = bR[q].x;
        Bl[(bh * 16 + q * 4 + 1) * 136 + bn] = bR[q].y;
        Bl[(bh * 16 + q * 4 + 2) * 136 + bn] = bR[q].z;
        Bl[(bh * 16 + q * 4 + 3) * 136 + bn] = bR[q].w;
      }
    } else {
#pragma unroll
      for (int q = 0; q < 4; ++q)
        *(float4*)(Bl + bk * 136 + bq * 4 + q * 32) = bR[q];
    }
    if (c + 1 < nch) {
      int kc = k0 + (c + 1) * 32;
      aR = *(const float4*)(X + (size_t)(xr0 + ar) * ldx + kc + aq * 4);
      if (TRANSB) {
#pragma unroll
        for (int q = 0; q < 4; ++q)
          bR[q] = *(const float4*)(Bp + (size_t)(n0 + bn) * ldb + kc + bh * 16 + q * 4);
      } else {
#pragma unroll
        for (int q = 0; q < 4; ++q)
          bR[q] = *(const float4*)(Bp + (size_t)(kc + bk) * ldb + n0 + bq * 4 + q * 32);
      }
    }
    __syncthreads();
#pragma unroll 4
    for (int k = 0; k < 32; ++k) {
      float4 a = *(const float4*)(A + k * 36 + tm * 4);
      float4 b = *(const float4*)(Bl + k * 136 + tn * 4);
      float av[4] = {a.x, a.y, a.z, a.w};
      float bv[4] = {b.x, b.y, b.z, b.w};
#pragma unroll
      for (int i = 0; i < 4; ++i)
#pragma unroll
        for (int j = 0; j < 4; ++j) acc[i][j] = fmaf(av[i], bv[j], acc[i][j]);
    }
  }
#pragma unroll
  for (int i = 0; i < 4; ++i) {
    float4 v; v.x = acc[i][0]; v.y = acc[i][1]; v.z = acc[i][2]; v.w = acc[i][3];
    *(float4*)(outp + (size_t)(or0 + tm * 4 + i) * ldo + n0 + tn * 4) = v;
  }
}

// ---------------- gen GEMM job: 32x128 tile, K=512, fused bias+mask+l1-store+partials
__device__ void gemm_gen(const float* __restrict__ hid, const float* __restrict__ outw,
                         const float* __restrict__ outbv, int bt, int nt, int step,
                         float* __restrict__ out, float* __restrict__ pm, float* __restrict__ pz,
                         float* __restrict__ pbl, int* __restrict__ pbi, float* lds) {
  const int tid = threadIdx.x;
  const int tm = tid >> 5, tn = tid & 31;
  const int n0 = nt * 128;
  float* Am = lds;
  float* Bm = lds + 2304;
  float acc[4][4] = {};
  const int ar = tid >> 3, aq = tid & 7;
  const int bn = tid >> 1, bh = tid & 1;
  float4 aR; float4 bR[4];
  {
    aR = *(const float4*)(hid + (size_t)(bt * 32 + ar) * HH + aq * 4);
#pragma unroll
    for (int q = 0; q < 4; ++q)
      bR[q] = *(const float4*)(outw + (size_t)(n0 + bn) * HH + bh * 16 + q * 4);
  }
  for (int c = 0; c < 16; ++c) {
    float* A = Am + (c & 1) * 1152;
    float* Bl = Bm + (c & 1) * 4352;
    A[(aq * 4 + 0) * 36 + ar] = aR.x;
    A[(aq * 4 + 1) * 36 + ar] = aR.y;
    A[(aq * 4 + 2) * 36 + ar] = aR.z;
    A[(aq * 4 + 3) * 36 + ar] = aR.w;
#pragma unroll
    for (int q = 0; q < 4; ++q) {
      Bl[(bh * 16 + q * 4 + 0) * 136 + bn] = bR[q].x;
      Bl[(bh * 16 + q * 4 + 1) * 136 + bn] = bR[q].y;
      Bl[(bh * 16 + q * 4 + 2) * 136 + bn] = bR[q].z;
      Bl[(bh * 16 + q * 4 + 3) * 136 + bn] = bR[q].w;
    }
    if (c + 1 < 16) {
      int kc = (c + 1) * 32;
      aR = *(const float4*)(hid + (size_t)(bt * 32 + ar) * HH + kc + aq * 4);
#pragma unroll
      for (int q = 0; q < 4; ++q)
        bR[q] = *(const float4*)(outw + (size_t)(n0 + bn) * HH + kc + bh * 16 + q * 4);
    }
    __syncthreads();
#pragma unroll 4
    for (int k = 0; k < 32; ++k) {
      float4 a = *(const float4*)(A + k * 36 + tm * 4);
      float4 b = *(const float4*)(Bl + k * 136 + tn * 4);
      float av[4] = {a.x, a.y, a.z, a.w};
      float bv[4] = {b.x, b.y, b.z, b.w};
#pragma unroll
      for (int i = 0; i < 4; ++i)
#pragma unroll
        for (int j = 0; j < 4; ++j) acc[i][j] = fmaf(av[i], bv[j], acc[i][j]);
    }
  }
  const float4 bias = *(const float4*)(outbv + n0 + tn * 4);
  const float bb4[4] = {bias.x, bias.y, bias.z, bias.w};
#pragma unroll
  for (int i = 0; i < 4; ++i) {
    float l[4];
#pragma unroll
    for (int j = 0; j < 4; ++j) l[j] = acc[i][j] + bb4[j];
    if (n0 == 0 && tn == 0) l[0] = -1e6f;  // global col 0
    const int bg = bt * 32 + tm * 4 + i;
    float4 st; st.x = l[0]; st.y = l[1]; st.z = l[2]; st.w = l[3];
    *(float4*)(out + ((size_t)bg * TT + step) * EXTW + n0 + tn * 4) = st;
    float m = fmaxf(fmaxf(l[0], l[1]), fmaxf(l[2], l[3]));
    m = rmax32(m);
    float z = expf(l[0] - m) + expf(l[1] - m) + expf(l[2] - m) + expf(l[3] - m);
    float blv = l[0]; int bli = n0 + tn * 4;
#pragma unroll
    for (int j = 1; j < 4; ++j)
      if (l[j] > blv) { blv = l[j]; bli = n0 + tn * 4 + j; }
    z = rsum32(z);
#pragma unroll
    for (int o = 1; o < 32; o <<= 1) {
      float ov = __shfl_xor(blv, o); int oi = __shfl_xor(bli, o);
      if (ov > blv || (ov == blv && oi < bli)) { blv = ov; bli = oi; }
    }
    if ((tid & 31) == 0) {
      pm[nt * 64 + bg] = m;
      pz[nt * 64 + bg] = z;
      pbl[nt * 64 + bg] = blv;
      pbi[nt * 64 + bg] = bli;
    }
  }
}

// ---------------- attention (scores via precomputed encA) -> context into rnn
__device__ void phaseAttn(int b, const float* __restrict__ hid, const float* __restrict__ enc,
                          const float* __restrict__ encA, const float* __restrict__ eba,
                          float* __restrict__ rnn, float* lds) {
  const int tid = threadIdx.x;
  float* hl = lds;          // 512
  float* sc = lds + 512;    // 128
  float* red = lds + 768;   // 256
  for (int i = tid; i < HH; i += NTHR) hl[i] = hid[(size_t)b * HH + i];
  __syncthreads();
  if (tid < SS) {
    const float* er = encA + ((size_t)b * SS + tid) * HH;
    float a = eba[b * SS + tid];
    for (int k = 0; k < HH; k += 4) {
      float4 e = *(const float4*)(er + k);
      a += e.x * hl[k] + e.y * hl[k + 1] + e.z * hl[k + 2] + e.w * hl[k + 3];
    }
    sc[tid] = a;
  }
  __syncthreads();
  red[tid] = (tid < SS) ? sc[tid] : -3.4e38f;
  __syncthreads();
  for (int s = 128; s > 0; s >>= 1) { if (tid < s) red[tid] = fmaxf(red[tid], red[tid + s]); __syncthreads(); }
  const float M = red[0];
  __syncthreads();
  float e = (tid < SS) ? expf(sc[tid] - M) : 0.f;
  red[tid] = e;
  __syncthreads();
  for (int s = 128; s > 0; s >>= 1) { if (tid < s) red[tid] += red[tid + s]; __syncthreads(); }
  const float Ssum = red[0];
  __syncthreads();
  if (tid < SS) sc[tid] = e / Ssum;
  __syncthreads();
  for (int h = tid; h < HH; h += NTHR) {
    float a = 0.f;
    for (int s = 0; s < SS; ++s) a += sc[s] * enc[((size_t)b * SS + s) * HH + h];
    rnn[(size_t)b * KX + h] = a;
  }
}

// ---------------- EF: css + scatter + softmax combine + argmax + ssw ----------------
__device__ void phaseEF(int b, int step, const float* __restrict__ hid,
                        const float* __restrict__ encC, const float* __restrict__ ebc,
                        const int* __restrict__ inp, float* __restrict__ out,
                        const float* __restrict__ pm, const float* __restrict__ pz,
                        const float* __restrict__ pbl, const int* __restrict__ pbi,
                        float* __restrict__ cd, float* __restrict__ ssw,
                        float* __restrict__ Mrow, float* __restrict__ Zrow,
                        int* __restrict__ biR, float* lds) {
  const int tid = threadIdx.x;
  float* hl = lds;                 // 512
  float* sc = lds + 512;           // 128
  int* il = (int*)(lds + 640);     // 128
  float* red = lds + 768;          // 256
  float* red2 = lds + 1024;        // 256
  int* redi = (int*)(lds + 1280);  // 256
  for (int i = tid; i < HH; i += NTHR) hl[i] = hid[(size_t)b * HH + i];
  if (tid < SS) il[tid] = inp[b * SS + tid];
  __syncthreads();
  if (tid < SS) {
    const float* er = encC + ((size_t)b * SS + tid) * HH;
    float a = ebc[b * SS + tid];
    for (int k = 0; k < HH; k += 4) {
      float4 e = *(const float4*)(er + k);
      a += e.x * hl[k] + e.y * hl[k + 1] + e.z * hl[k + 2] + e.w * hl[k + 3];
    }
    sc[tid] = a;
  }
  __syncthreads();
  float myl2 = -3.4e38f; int mytok = -1; bool first = false;
  if (tid < SS) {
    int tok = il[tid];
    if (tok != 0) {
      first = true;
      for (int s2 = 0; s2 < tid; ++s2)
        if (il[s2] == tok) { first = false; break; }
      if (first) {
        float v = 0.f;
        for (int s2 = tid; s2 < SS; ++s2)
          if (il[s2] == tok) v += sc[s2];
        cd[(size_t)b * VV + tok] = v;
        myl2 = v; mytok = tok;
      }
    }
  }
  // ---- global max M over gen-tile maxes and present copy scores
  float lm = -3.4e38f;
  if (tid < 250) lm = pm[tid * 64 + b];
  if (first) lm = fmaxf(lm, myl2);
  red[tid] = lm;
  __syncthreads();
  for (int s = 128; s > 0; s >>= 1) { if (tid < s) red[tid] = fmaxf(red[tid], red[tid + s]); __syncthreads(); }
  const float M = red[0];
  __syncthreads();
  // ---- Z and gen-best (max logit, tie -> min index)
  float lz = 0.f; float lbl = -3.4e38f; int lbi = 0x7fffffff;
  if (tid < 250) {
    lz = pz[tid * 64 + b] * expf(pm[tid * 64 + b] - M);
    lbl = pbl[tid * 64 + b];
    lbi = pbi[tid * 64 + b];
  }
  if (first) lz += expf(myl2 - M);
  red[tid] = lz; red2[tid] = lbl; redi[tid] = lbi;
  __syncthreads();
  for (int s = 128; s > 0; s >>= 1) {
    if (tid < s) {
      red[tid] += red[tid + s];
      float ov = red2[tid + s]; int oi = redi[tid + s];
      if (ov > red2[tid] || (ov == red2[tid] && oi < redi[tid])) { red2[tid] = ov; redi[tid] = oi; }
    }
    __syncthreads();
  }
  const float Z = red[0];
  const float bl = red2[0]; const int bli = redi[0];
  __syncthreads();
  // ---- candidates: gen-best and each present copy token (full value exp(l1-M)+exp(l2-M))
  float cv = -1.f; int ci = 0x7fffffff;
  if (tid == 0) { cv = expf(bl - M); ci = bli; }
  if (first) {
    float l1 = out[((size_t)b * TT + step) * EXTW + mytok];
    float v = expf(l1 - M) + expf(myl2 - M);
    if (v > cv || (v == cv && mytok < ci)) { cv = v; ci = mytok; }
  }
  red2[tid] = cv; redi[tid] = ci;
  __syncthreads();
  for (int s = 128; s > 0; s >>= 1) {
    if (tid < s) {
      float ov = red2[tid + s]; int oi = redi[tid + s];
      if (ov > red2[tid] || (ov == red2[tid] && oi < redi[tid])) { red2[tid] = ov; redi[tid] = oi; }
    }
    __syncthreads();
  }
  const int bi_f = redi[0];
  if (tid == 0) {
    Mrow[b] = M; Zrow[b] = Z; biR[b] = bi_f;
    out[(size_t)BB * TT * EXTW + (size_t)b * TT + step] = (float)bi_f;
  }
  __syncthreads();
  // ---- ssw = normalized (pos * css)
  if (tid < SS) sc[tid] = (il[tid] == bi_f) ? sc[tid] : 0.f;
  __syncthreads();
  red[tid] = (tid < SS) ? fabsf(sc[tid]) : 0.f;
  __syncthreads();
  for (int s = 128; s > 0; s >>= 1) { if (tid < s) red[tid] += red[tid + s]; __syncthreads(); }
  const float norm = fmaxf(red[0], 1e-12f);
  __syncthreads();
  if (tid < SS) ssw[b * SS + tid] = sc[tid] / norm;
}

// ---------------- main persistent kernel ----------------
__global__ __launch_bounds__(NTHR, 2) void copynet(
    const float* __restrict__ enc, const int* __restrict__ inp,
    const float* __restrict__ embw,
    const float* __restrict__ attnw, const float* __restrict__ attnb,
    const float* __restrict__ copyw, const float* __restrict__ copyb,
    const float* __restrict__ wih, const float* __restrict__ whh,
    const float* __restrict__ bih, const float* __restrict__ bhh,
    const float* __restrict__ outw, const float* __restrict__ outbv,
    float* __restrict__ out, u32* __restrict__ wsu) {
  __shared__ __align__(16) float lds[11008];
  u32* bar = wsu;
  float* ws = (float*)wsu + 256;
  float* hid = ws;                    // 64*512
  float* rnn = hid + 32768;           // 64*1280 : ctx | sel | emb
  float* gip = rnn + 81920;           // 4 * 64*1536
  float* ghp = gip + 393216;          // 2 * 64*1536
  float* cd = ghp + 196608;           // 64*32000
  float* ssw = cd + 2048000;          // 64*128
  float* pm = ssw + 8192;             // 250*64
  float* pz = pm + 16000;
  float* pbl = pz + 16000;
  int* pbi = (int*)(pbl + 16000);
  float* Mrow = pbl + 32000;
  float* Zrow = Mrow + 64;
  float* biRf = Zrow + 64;
  int* biR = (int*)biRf;
  float* eba = biRf + 64;             // 64*128
  float* ebc = eba + 8192;            // 64*128
  float* encA = ebc + 8192;           // 8192*512
  float* encC = encA + 4194304;       // 8192*512

  const int blk = blockIdx.x, tid = threadIdx.x;
  const size_t gt = (size_t)blk * NTHR + tid;
  const size_t gs = (size_t)NBLK * NTHR;

  // ---- P0: init state
  for (size_t i = gt; i < 32768; i += gs) hid[i] = 0.f;
  for (size_t i = gt; i < 65536; i += gs) { size_t b = i >> 10, k = i & 1023; rnn[b * KX + k] = 0.f; }
  for (size_t i = gt; i < 16384; i += gs) { size_t b = i >> 8, e = i & 255; rnn[b * KX + 1024 + e] = embw[256 + e]; }
  for (size_t i = gt; i < 2048000; i += gs) cd[i] = -1e6f;
  for (size_t i = gt; i < (size_t)BB * EXTW; i += gs) {
    size_t b = i / EXTW, j = i % EXTW;
    out[b * TT * EXTW + j] = (j == 1) ? 1.f : 0.f;
  }
  for (size_t i = gt; i < 64; i += gs) out[(size_t)BB * TT * EXTW + i * TT] = 1.f;
  // ---- P1: encA = enc@attnw, encC = enc@copyw (gemm_nn), eba/ebc dots
  for (int job = blk; job < 2048; job += NBLK) {
    int w = job >> 10;
    int t = job & 1023;
    int mt = t >> 2, ntl = t & 3;
    gemm_t<false>(enc, HH, mt * 32, w ? copyw : attnw, HH, ntl * 128, 0, 16,
                  w ? encC : encA, HH, mt * 32, lds);
  }
  if (blk < 64 && tid < SS) {
    const float* er = enc + ((size_t)blk * SS + tid) * HH;
    float a1 = 0.f, a2 = 0.f;
    for (int k = 0; k < HH; k += 4) {
      float4 e = *(const float4*)(er + k);
      a1 += e.x * attnb[k] + e.y * attnb[k + 1] + e.z * attnb[k + 2] + e.w * attnb[k + 3];
      a2 += e.x * copyb[k] + e.y * copyb[k + 1] + e.z * copyb[k + 2] + e.w * copyb[k + 3];
    }
    eba[blk * SS + tid] = a1;
    ebc[blk * SS + tid] = a2;
  }
  gsync(bar);
  // ---- A0: initial attention (h=0)
  if (blk < 64) phaseAttn(blk, hid, enc, encA, eba, rnn, lds);
  gsync(bar);

  for (int step = 1; step < TT; ++step) {
    // B: GRU GEMM partials. gi: 96 jobs (K=320 x4), gh: 48 jobs (K=256 x2)
    for (int job = blk; job < 144; job += NBLK) {
      if (job < 96) {
        int bt = job & 1, nt = (job >> 1) % 12, ks = job / 24;
        gemm_t<true>(rnn, KX, bt * 32, wih, KX, nt * 128, ks * 320, 10,
                     gip + (size_t)ks * 98304, 1536, bt * 32, lds);
      } else {
        int t = job - 96;
        int bt = t & 1, nt = (t >> 1) % 12, ks = t / 24;
        gemm_t<true>(hid, HH, bt * 32, whh, HH, nt * 128, ks * 256, 8,
                     ghp + (size_t)ks * 98304, 1536, bt * 32, lds);
      }
    }
    gsync(bar);
    // C: GRU elementwise -> hid
    {
      int t = blk * NTHR + tid;
      if (t < BB * HH) {
        int b = t >> 9, g = t & 511;
        float gir = bih[g], giz = bih[512 + g], gin = bih[1024 + g];
#pragma unroll
        for (int ks = 0; ks < 4; ++ks) {
          const float* p = gip + (size_t)ks * 98304 + (size_t)b * 1536;
          gir += p[g]; giz += p[512 + g]; gin += p[1024 + g];
        }
        float ghr = bhh[g], ghz = bhh[512 + g], ghn = bhh[1024 + g];
#pragma unroll
        for (int ks = 0; ks < 2; ++ks) {
          const float* p = ghp + (size_t)ks * 98304 + (size_t)b * 1536;
          ghr += p[g]; ghz += p[512 + g]; ghn += p[1024 + g];
        }
        float rr = 1.f / (1.f + expf(-(gir + ghr)));
        float zz = 1.f / (1.f + expf(-(giz + ghz)));
        float nn = tanhf(gin + rr * ghn);
        hid[t] = (1.f - zz) * nn + zz * hid[t];
      }
    }
    gsync(bar);
    // D: gen logits (500 jobs, 32x128, K=512) -> l1 into out + fused partials
    for (int job = blk; job < 500; job += NBLK) {
      int bt = job / 250, nt = job % 250;
      gemm_gen(hid, outw, outbv, bt, nt, step, out, pm, pz, pbl, pbi, lds);
    }
    gsync(bar);
    // EF: copy scores, scatter, combine, argmax, ssw
    if (blk < 64)
      phaseEF(blk, step, hid, encC, ebc, inp, out, pm, pz, pbl, pbi,
              cd, ssw, Mrow, Zrow, biR, lds);
    gsync(bar);
    // G: logp in-place + (c0) sel+emb + (c1) next attention
    {
      const int r = blk & 63, c = blk >> 6;
      const float M = Mrow[r], Z = Zrow[r];
      const int j0 = (c < 2) ? c * 2432 : 4864 + (c - 2) * 4544;
      const int jend = (c < 1) ? 2432 : ((c < 2) ? 4864 : 4864 + (c - 1) * 4544);
      float* orow = out + ((size_t)r * TT + step) * EXTW;
      const float* cdr = cd + (size_t)r * VV;
      const float LPT = logf(1e-10f);
      for (int j = j0 + tid; j < jend; j += NTHR) {
        float lp;
        if (j < VV) {
          float v = expf(orow[j] - M) + expf(cdr[j] - M);
          lp = logf(v / Z + 1e-10f);
        } else lp = LPT;
        orow[j] = lp;
      }
      if (c == 0) {
        float* sw = lds;
        if (tid < SS) sw[tid] = ssw[r * SS + tid];
        __syncthreads();
        for (int h = tid; h < HH; h += NTHR) {
          float a = 0.f;
          for (int s = 0; s < SS; ++s) a += sw[s] * enc[((size_t)r * SS + s) * HH + h];
          rnn[(size_t)r * KX + 512 + h] = a;
        }
        int bi = biR[r];
        int ic = (bi > VV) ? 3 : bi;
        if (ic >= VV) ic = VV - 1;
        if (tid < EE) rnn[(size_t)r * KX + 1024 + tid] = embw[(size_t)ic * EE + tid];
      } else if (c == 1) {
        phaseAttn(r, hid, enc, encA, eba, rnn, lds);
      }
    }
    gsync(bar);
  }
}

extern "C" void kernel_launch(void* const* d_in, const int* in_sizes, int n_in,
                              void* d_out, int out_size, void* d_ws, size_t ws_size,
                              hipStream_t stream) {
  const float* enc = (const float*)d_in[0];
  const int* inp = (const int*)d_in[1];
  const float* embw = (const float*)d_in[3];
  const float* attnw = (const float*)d_in[4];
  const float* attnb = (const float*)d_in[5];
  const float* copyw = (const float*)d_in[6];
  const float* copyb = (const float*)d_in[7];
  const float* wih = (const float*)d_in[8];
  const float* whh = (const float*)d_in[9];
  const float* bih = (const float*)d_in[10];
  const float* bhh = (const float*)d_in[11];
  const float* outw = (const float*)d_in[12];
  const float* outb = (const float*)d_in[13];
  (void)in_sizes; (void)n_in; (void)out_size; (void)ws_size;
  hipMemsetAsync(d_ws, 0, 1024, stream);
  copynet<<<dim3(NBLK), dim3(NTHR), 0, stream>>>(
      enc, inp, embw, attnw, attnb, copyw, copyb,
      wih, whh, bih, bhh, outw, outb,
      (float*)d_out, (u32*)d_ws);
}

// Round 4
// 6718.460 us; speedup vs baseline: 5.0840x; 2.4979x over previous
//
#include <hip/hip_runtime.h>
#include <math.h>

#define NBLK 768
#define NTHR 256
#define BB 64
#define SS 128
#define HH 512
#define EE 256
#define VV 32000
#define TT 32
#define EXTW 32128
#define KX 1280

typedef unsigned int u32;

// ---------------- 2-level grid barrier; relaxed polling + acquire fence ----------------
__device__ __forceinline__ void gsync(u32* bar) {
  __syncthreads();
  if (threadIdx.x == 0) {
    u32* gcnt = bar + (blockIdx.x >> 6) * 16;   // 12 groups of 64
    u32* mast = bar + 192;
    u32* gene = bar + 208;
    u32 g = __hip_atomic_load(gene, __ATOMIC_RELAXED, __HIP_MEMORY_SCOPE_AGENT);
    bool last = false;
    if (__hip_atomic_fetch_add(gcnt, 1u, __ATOMIC_ACQ_REL, __HIP_MEMORY_SCOPE_AGENT) == 63u) {
      __hip_atomic_store(gcnt, 0u, __ATOMIC_RELAXED, __HIP_MEMORY_SCOPE_AGENT);
      if (__hip_atomic_fetch_add(mast, 1u, __ATOMIC_ACQ_REL, __HIP_MEMORY_SCOPE_AGENT) == 11u) {
        __hip_atomic_store(mast, 0u, __ATOMIC_RELAXED, __HIP_MEMORY_SCOPE_AGENT);
        __hip_atomic_store(gene, g + 1u, __ATOMIC_RELEASE, __HIP_MEMORY_SCOPE_AGENT);
        last = true;
      }
    }
    if (!last) {
      while (__hip_atomic_load(gene, __ATOMIC_RELAXED, __HIP_MEMORY_SCOPE_AGENT) == g)
        __builtin_amdgcn_s_sleep(4);
      __builtin_amdgcn_fence(__ATOMIC_ACQUIRE, "agent");
    }
  }
  __syncthreads();
}

__device__ __forceinline__ float rmax32(float v) {
#pragma unroll
  for (int o = 1; o < 32; o <<= 1) v = fmaxf(v, __shfl_xor(v, o));
  return v;
}
__device__ __forceinline__ float rsum32(float v) {
#pragma unroll
  for (int o = 1; o < 32; o <<= 1) v += __shfl_xor(v, o);
  return v;
}

// ---------------- 32x128 tile GEMM, K chunked by 32, reg-prefetch + LDS dbuf ----
template<bool TRANSB>
__device__ void gemm_t(const float* __restrict__ X, int ldx, int xr0,
                       const float* __restrict__ Bp, int ldb, int n0, int k0, int nch,
                       float* __restrict__ outp, int ldo, int or0, float* lds) {
  const int tid = threadIdx.x;
  const int tm = tid >> 5, tn = tid & 31;
  float* Am = lds;
  float* Bm = lds + 2304;
  float acc[4][4] = {};
  const int ar = tid >> 3, aq = tid & 7;
  const int bn = tid >> 1, bh = tid & 1;
  const int bk = tid >> 3, bq = tid & 7;
  float4 aR; float4 bR[4];
  {
    int kc = k0;
    aR = *(const float4*)(X + (size_t)(xr0 + ar) * ldx + kc + aq * 4);
    if (TRANSB) {
#pragma unroll
      for (int q = 0; q < 4; ++q)
        bR[q] = *(const float4*)(Bp + (size_t)(n0 + bn) * ldb + kc + bh * 16 + q * 4);
    } else {
#pragma unroll
      for (int q = 0; q < 4; ++q)
        bR[q] = *(const float4*)(Bp + (size_t)(kc + bk) * ldb + n0 + bq * 4 + q * 32);
    }
  }
  for (int c = 0; c < nch; ++c) {
    float* A = Am + (c & 1) * 1152;
    float* Bl = Bm + (c & 1) * 4352;
    A[(aq * 4 + 0) * 36 + ar] = aR.x;
    A[(aq * 4 + 1) * 36 + ar] = aR.y;
    A[(aq * 4 + 2) * 36 + ar] = aR.z;
    A[(aq * 4 + 3) * 36 + ar] = aR.w;
    if (TRANSB) {
#pragma unroll
      for (int q = 0; q < 4; ++q) {
        Bl[(bh * 16 + q * 4 + 0) * 136 + bn] = bR[q].x;
        Bl[(bh * 16 + q * 4 + 1) * 136 + bn] = bR[q].y;
        Bl[(bh * 16 + q * 4 + 2) * 136 + bn] = bR[q].z;
        Bl[(bh * 16 + q * 4 + 3) * 136 + bn] = bR[q].w;
      }
    } else {
#pragma unroll
      for (int q = 0; q < 4; ++q)
        *(float4*)(Bl + bk * 136 + bq * 4 + q * 32) = bR[q];
    }
    if (c + 1 < nch) {
      int kc = k0 + (c + 1) * 32;
      aR = *(const float4*)(X + (size_t)(xr0 + ar) * ldx + kc + aq * 4);
      if (TRANSB) {
#pragma unroll
        for (int q = 0; q < 4; ++q)
          bR[q] = *(const float4*)(Bp + (size_t)(n0 + bn) * ldb + kc + bh * 16 + q * 4);
      } else {
#pragma unroll
        for (int q = 0; q < 4; ++q)
          bR[q] = *(const float4*)(Bp + (size_t)(kc + bk) * ldb + n0 + bq * 4 + q * 32);
      }
    }
    __syncthreads();
#pragma unroll 4
    for (int k = 0; k < 32; ++k) {
      float4 a = *(const float4*)(A + k * 36 + tm * 4);
      float4 b = *(const float4*)(Bl + k * 136 + tn * 4);
      float av[4] = {a.x, a.y, a.z, a.w};
      float bv[4] = {b.x, b.y, b.z, b.w};
#pragma unroll
      for (int i = 0; i < 4; ++i)
#pragma unroll
        for (int j = 0; j < 4; ++j) acc[i][j] = fmaf(av[i], bv[j], acc[i][j]);
    }
  }
#pragma unroll
  for (int i = 0; i < 4; ++i) {
    float4 v; v.x = acc[i][0]; v.y = acc[i][1]; v.z = acc[i][2]; v.w = acc[i][3];
    *(float4*)(outp + (size_t)(or0 + tm * 4 + i) * ldo + n0 + tn * 4) = v;
  }
}

// ---------------- gen GEMM job: 32x128, K=512; store l1 to genp + tile partials ----
__device__ void gemm_gen(const float* __restrict__ hid, const float* __restrict__ outw,
                         const float* __restrict__ outbv, int bt, int nt,
                         float* __restrict__ genp, float* __restrict__ pm, float* __restrict__ pz,
                         float* __restrict__ pbl, int* __restrict__ pbi, float* lds) {
  const int tid = threadIdx.x;
  const int tm = tid >> 5, tn = tid & 31;
  const int n0 = nt * 128;
  float* Am = lds;
  float* Bm = lds + 2304;
  float acc[4][4] = {};
  const int ar = tid >> 3, aq = tid & 7;
  const int bn = tid >> 1, bh = tid & 1;
  float4 aR; float4 bR[4];
  {
    aR = *(const float4*)(hid + (size_t)(bt * 32 + ar) * HH + aq * 4);
#pragma unroll
    for (int q = 0; q < 4; ++q)
      bR[q] = *(const float4*)(outw + (size_t)(n0 + bn) * HH + bh * 16 + q * 4);
  }
  for (int c = 0; c < 16; ++c) {
    float* A = Am + (c & 1) * 1152;
    float* Bl = Bm + (c & 1) * 4352;
    A[(aq * 4 + 0) * 36 + ar] = aR.x;
    A[(aq * 4 + 1) * 36 + ar] = aR.y;
    A[(aq * 4 + 2) * 36 + ar] = aR.z;
    A[(aq * 4 + 3) * 36 + ar] = aR.w;
#pragma unroll
    for (int q = 0; q < 4; ++q) {
      Bl[(bh * 16 + q * 4 + 0) * 136 + bn] = bR[q].x;
      Bl[(bh * 16 + q * 4 + 1) * 136 + bn] = bR[q].y;
      Bl[(bh * 16 + q * 4 + 2) * 136 + bn] = bR[q].z;
      Bl[(bh * 16 + q * 4 + 3) * 136 + bn] = bR[q].w;
    }
    if (c + 1 < 16) {
      int kc = (c + 1) * 32;
      aR = *(const float4*)(hid + (size_t)(bt * 32 + ar) * HH + kc + aq * 4);
#pragma unroll
      for (int q = 0; q < 4; ++q)
        bR[q] = *(const float4*)(outw + (size_t)(n0 + bn) * HH + kc + bh * 16 + q * 4);
    }
    __syncthreads();
#pragma unroll 4
    for (int k = 0; k < 32; ++k) {
      float4 a = *(const float4*)(A + k * 36 + tm * 4);
      float4 b = *(const float4*)(Bl + k * 136 + tn * 4);
      float av[4] = {a.x, a.y, a.z, a.w};
      float bv[4] = {b.x, b.y, b.z, b.w};
#pragma unroll
      for (int i = 0; i < 4; ++i)
#pragma unroll
        for (int j = 0; j < 4; ++j) acc[i][j] = fmaf(av[i], bv[j], acc[i][j]);
    }
  }
  const float4 bias = *(const float4*)(outbv + n0 + tn * 4);
  const float bb4[4] = {bias.x, bias.y, bias.z, bias.w};
#pragma unroll
  for (int i = 0; i < 4; ++i) {
    float l[4];
#pragma unroll
    for (int j = 0; j < 4; ++j) l[j] = acc[i][j] + bb4[j];
    if (n0 == 0 && tn == 0) l[0] = -1e6f;  // mask global col 0
    const int bg = bt * 32 + tm * 4 + i;
    float4 st; st.x = l[0]; st.y = l[1]; st.z = l[2]; st.w = l[3];
    *(float4*)(genp + (size_t)bg * VV + n0 + tn * 4) = st;
    float m = fmaxf(fmaxf(l[0], l[1]), fmaxf(l[2], l[3]));
    m = rmax32(m);
    float z = expf(l[0] - m) + expf(l[1] - m) + expf(l[2] - m) + expf(l[3] - m);
    float blv = l[0]; int bli = n0 + tn * 4;
#pragma unroll
    for (int j = 1; j < 4; ++j)
      if (l[j] > blv) { blv = l[j]; bli = n0 + tn * 4 + j; }
    z = rsum32(z);
#pragma unroll
    for (int o = 1; o < 32; o <<= 1) {
      float ov = __shfl_xor(blv, o); int oi = __shfl_xor(bli, o);
      if (ov > blv || (ov == blv && oi < bli)) { blv = ov; bli = oi; }
    }
    if ((tid & 31) == 0) {
      pm[bg * 256 + nt] = m;
      pz[bg * 256 + nt] = z;
      pbl[bg * 256 + nt] = blv;
      pbi[bg * 256 + nt] = bli;
    }
  }
}

// ---------------- attention (scores via precomputed encA) -> context into rnn
__device__ void phaseAttn(int b, const float* __restrict__ hid, const float* __restrict__ enc,
                          const float* __restrict__ encA, const float* __restrict__ eba,
                          float* __restrict__ rnn, float* lds) {
  const int tid = threadIdx.x;
  float* hl = lds;          // 512
  float* sc = lds + 512;    // 128
  float* red = lds + 768;   // 256
  for (int i = tid; i < HH; i += NTHR) hl[i] = hid[(size_t)b * HH + i];
  __syncthreads();
  if (tid < SS) {
    const float* er = encA + ((size_t)b * SS + tid) * HH;
    float a = eba[b * SS + tid];
    for (int k = 0; k < HH; k += 4) {
      float4 e = *(const float4*)(er + k);
      a += e.x * hl[k] + e.y * hl[k + 1] + e.z * hl[k + 2] + e.w * hl[k + 3];
    }
    sc[tid] = a;
  }
  __syncthreads();
  red[tid] = (tid < SS) ? sc[tid] : -3.4e38f;
  __syncthreads();
  for (int s = 128; s > 0; s >>= 1) { if (tid < s) red[tid] = fmaxf(red[tid], red[tid + s]); __syncthreads(); }
  const float M = red[0];
  __syncthreads();
  float e = (tid < SS) ? expf(sc[tid] - M) : 0.f;
  red[tid] = e;
  __syncthreads();
  for (int s = 128; s > 0; s >>= 1) { if (tid < s) red[tid] += red[tid + s]; __syncthreads(); }
  const float Ssum = red[0];
  __syncthreads();
  if (tid < SS) sc[tid] = e / Ssum;
  __syncthreads();
  for (int h = tid; h < HH; h += NTHR) {
    float a = 0.f;
    for (int s = 0; s < SS; ++s) a += sc[s] * enc[((size_t)b * SS + s) * HH + h];
    rnn[(size_t)b * KX + h] = a;
  }
}

// ---------------- css job: copy scores + sparse scatter (per-row lists) -------
__device__ void cssJob(int b, const float* __restrict__ hid,
                       const float* __restrict__ encC, const float* __restrict__ ebc,
                       const int* __restrict__ inp, const int* __restrict__ cnt,
                       const int* __restrict__ toks, float* __restrict__ cvals,
                       float* __restrict__ cdD, float* __restrict__ cssg, float* lds) {
  const int tid = threadIdx.x;
  float* hl = lds;              // 512
  float* sc = lds + 512;        // 128
  int* il = (int*)(lds + 640);  // 128
  for (int i = tid; i < HH; i += NTHR) hl[i] = hid[(size_t)b * HH + i];
  if (tid < SS) il[tid] = inp[b * SS + tid];
  __syncthreads();
  if (tid < SS) {
    const float* er = encC + ((size_t)b * SS + tid) * HH;
    float a = ebc[b * SS + tid];
    for (int k = 0; k < HH; k += 4) {
      float4 e = *(const float4*)(er + k);
      a += e.x * hl[k] + e.y * hl[k + 1] + e.z * hl[k + 2] + e.w * hl[k + 3];
    }
    sc[tid] = a;
    cssg[b * SS + tid] = a;
  }
  __syncthreads();
  const int cn = cnt[b];
  if (tid < cn) {
    int tok = toks[b * SS + tid];
    float v = 0.f;
    for (int s = 0; s < SS; ++s)
      if (il[s] == tok) v += sc[s];
    cvals[b * SS + tid] = v;
    cdD[(size_t)b * VV + tok] = v;
  }
}

// ---------------- main persistent kernel ----------------
__global__ __launch_bounds__(NTHR, 3) void copynet(
    const float* __restrict__ enc, const int* __restrict__ inp,
    const float* __restrict__ embw,
    const float* __restrict__ attnw, const float* __restrict__ attnb,
    const float* __restrict__ copyw, const float* __restrict__ copyb,
    const float* __restrict__ wih, const float* __restrict__ whh,
    const float* __restrict__ bih, const float* __restrict__ bhh,
    const float* __restrict__ outw, const float* __restrict__ outbv,
    float* __restrict__ out, u32* __restrict__ wsu) {
  __shared__ __align__(16) float lds[11008];
  u32* bar = wsu;
  float* ws = (float*)wsu + 256;
  float* hid  = ws;                    // 64*512
  float* rnn  = hid + 32768;           // 64*1280 : ctx | sel | emb
  float* gip  = rnn + 81920;           // 4 * 64*1536
  float* ghp  = gip + 393216;          // 2 * 64*1536
  float* genp = ghp + 196608;          // 64*32000 raw logits (hot)
  float* cdD  = genp + 2048000;        // 64*32000 sparse copy scores
  float* cssg = cdD + 2048000;         // 64*128
  float* pm   = cssg + 8192;           // 64*256 (250 used)
  float* pz   = pm + 16384;
  float* pbl  = pz + 16384;
  int*   pbi  = (int*)(pbl + 16384);
  int*   cnt  = (int*)(pbi + 16384);   // 64
  int*   toks = cnt + 64;              // 64*128
  float* cvals = (float*)(toks + 8192);// 64*128
  u32*   isP  = (u32*)(cvals + 8192);  // 64*1000 bitmap
  float* eba  = (float*)(isP + 64000); // 64*128
  float* ebc  = eba + 8192;            // 64*128
  float* encA = ebc + 8192;            // 8192*512
  float* encC = encA + 4194304;        // 8192*512

  const int blk = blockIdx.x, tid = threadIdx.x;
  const size_t gt = (size_t)blk * NTHR + tid;
  const size_t gs = (size_t)NBLK * NTHR;
  const float LPT = logf(1e-10f);

  // ---- P0/P1: init state, bitmap zero, out init (NT stores), encA/encC, eba/ebc
  for (size_t i = gt; i < 32768; i += gs) hid[i] = 0.f;
  for (size_t i = gt; i < 65536; i += gs) { size_t b = i >> 10, k = i & 1023; rnn[b * KX + k] = 0.f; }
  for (size_t i = gt; i < 16384; i += gs) { size_t b = i >> 8, e = i & 255; rnn[b * KX + 1024 + e] = embw[256 + e]; }
  for (size_t i = gt; i < 64000; i += gs) isP[i] = 0u;
  for (size_t i = gt; i < (size_t)BB * EXTW; i += gs) {
    size_t b = i / EXTW, j = i % EXTW;
    __builtin_nontemporal_store((j == 1) ? 1.f : 0.f, out + b * TT * EXTW + j);
  }
  for (size_t i = gt; i < 64; i += gs) out[(size_t)BB * TT * EXTW + i * TT] = 1.f;
  for (int job = blk; job < 2048; job += NBLK) {
    int w = job >> 10;
    int t = job & 1023;
    int mt = t >> 2, ntl = t & 3;
    gemm_t<false>(enc, HH, mt * 32, w ? copyw : attnw, HH, ntl * 128, 0, 16,
                  w ? encC : encA, HH, mt * 32, lds);
  }
  if (blk < 64 && tid < SS) {
    const float* er = enc + ((size_t)blk * SS + tid) * HH;
    float a1 = 0.f, a2 = 0.f;
    for (int k = 0; k < HH; k += 4) {
      float4 e = *(const float4*)(er + k);
      a1 += e.x * attnb[k] + e.y * attnb[k + 1] + e.z * attnb[k + 2] + e.w * attnb[k + 3];
      a2 += e.x * copyb[k] + e.y * copyb[k + 1] + e.z * copyb[k + 2] + e.w * copyb[k + 3];
    }
    eba[blk * SS + tid] = a1;
    ebc[blk * SS + tid] = a2;
  }
  gsync(bar);
  // ---- A0: initial attention (blocks 0..63) + per-row token lists (blocks 64..127)
  if (blk < 64) {
    phaseAttn(blk, hid, enc, encA, eba, rnn, lds);
  } else if (blk < 128) {
    const int b = blk - 64;
    int* il = (int*)lds;
    int* lcnt = il + 160;
    if (tid < SS) il[tid] = inp[b * SS + tid];
    if (tid == 0) *lcnt = 0;
    __syncthreads();
    if (tid < SS) {
      int tok = il[tid];
      if (tok != 0) {
        bool first = true;
        for (int s2 = 0; s2 < tid; ++s2)
          if (il[s2] == tok) { first = false; break; }
        if (first) {
          int k = atomicAdd(lcnt, 1);
          toks[b * SS + k] = tok;
          atomicOr(&isP[b * 1000 + (tok >> 5)], 1u << (tok & 31));
        }
      }
    }
    __syncthreads();
    if (tid == 0) cnt[b] = *lcnt;
  }
  gsync(bar);

  for (int step = 1; step < TT; ++step) {
    // B: GRU GEMM partials (144 jobs)
    for (int job = blk; job < 144; job += NBLK) {
      if (job < 96) {
        int bt = job & 1, nt = (job >> 1) % 12, ks = job / 24;
        gemm_t<true>(rnn, KX, bt * 32, wih, KX, nt * 128, ks * 320, 10,
                     gip + (size_t)ks * 98304, 1536, bt * 32, lds);
      } else {
        int t = job - 96;
        int bt = t & 1, nt = (t >> 1) % 12, ks = t / 24;
        gemm_t<true>(hid, HH, bt * 32, whh, HH, nt * 128, ks * 256, 8,
                     ghp + (size_t)ks * 98304, 1536, bt * 32, lds);
      }
    }
    gsync(bar);
    // C: GRU elementwise -> hid
    {
      int t = blk * NTHR + tid;
      if (t < BB * HH) {
        int b = t >> 9, g = t & 511;
        float gir = bih[g], giz = bih[512 + g], gin = bih[1024 + g];
#pragma unroll
        for (int ks = 0; ks < 4; ++ks) {
          const float* p = gip + (size_t)ks * 98304 + (size_t)b * 1536;
          gir += p[g]; giz += p[512 + g]; gin += p[1024 + g];
        }
        float ghr = bhh[g], ghz = bhh[512 + g], ghn = bhh[1024 + g];
#pragma unroll
        for (int ks = 0; ks < 2; ++ks) {
          const float* p = ghp + (size_t)ks * 98304 + (size_t)b * 1536;
          ghr += p[g]; ghz += p[512 + g]; ghn += p[1024 + g];
        }
        float rr = 1.f / (1.f + expf(-(gir + ghr)));
        float zz = 1.f / (1.f + expf(-(giz + ghz)));
        float nn = tanhf(gin + rr * ghn);
        hid[t] = (1.f - zz) * nn + zz * hid[t];
      }
    }
    gsync(bar);
    // D': gen logits (500 jobs) + css jobs (64)
    for (int job = blk; job < 564; job += NBLK) {
      if (job < 500) {
        int bt = job / 250, nt = job % 250;
        gemm_gen(hid, outw, outbv, bt, nt, genp, pm, pz, pbl, pbi, lds);
      } else {
        cssJob(job - 500, hid, encC, ebc, inp, cnt, toks, cvals, cdD, cssg, lds);
      }
    }
    gsync(bar);
    // G': per-row M/Z (all blocks, redundant), c0: argmax+ssw/sel/emb, c1: next attn,
    //     all: logp chunk written ONCE with nontemporal stores
    {
      const int r = blk & 63, c = blk >> 6;   // c in 0..11
      float* red = lds;
      float* red2 = lds + 256;
      int* redi = (int*)(lds + 512);
      const int cn = cnt[r];
      float lm = -3.4e38f;
      if (tid < 250) lm = pm[r * 256 + tid];
      if (tid < cn) lm = fmaxf(lm, cvals[r * SS + tid]);
      red[tid] = lm;
      __syncthreads();
      for (int s = 128; s > 0; s >>= 1) { if (tid < s) red[tid] = fmaxf(red[tid], red[tid + s]); __syncthreads(); }
      const float M = red[0];
      __syncthreads();
      float lz = 0.f;
      if (tid < 250) lz = pz[r * 256 + tid] * expf(pm[r * 256 + tid] - M);
      if (tid < cn) lz += expf(cvals[r * SS + tid] - M);
      red[tid] = lz;
      __syncthreads();
      for (int s = 128; s > 0; s >>= 1) { if (tid < s) red[tid] += red[tid + s]; __syncthreads(); }
      const float Z = red[0];
      __syncthreads();
      int bi_f = 0;
      if (c == 0) {
        float cv = -1.f; int ci = 0x7fffffff;
        if (tid < 250) { cv = expf(pbl[r * 256 + tid] - M); ci = pbi[r * 256 + tid]; }
        if (tid < cn) {
          int tok = toks[r * SS + tid];
          float v = expf(genp[(size_t)r * VV + tok] - M) + expf(cvals[r * SS + tid] - M);
          if (v > cv || (v == cv && tok < ci)) { cv = v; ci = tok; }
        }
        red2[tid] = cv; redi[tid] = ci;
        __syncthreads();
        for (int s = 128; s > 0; s >>= 1) {
          if (tid < s) {
            float ov = red2[tid + s]; int oi = redi[tid + s];
            if (ov > red2[tid] || (ov == red2[tid] && oi < redi[tid])) { red2[tid] = ov; redi[tid] = oi; }
          }
          __syncthreads();
        }
        bi_f = redi[0];
        if (tid == 0) out[(size_t)BB * TT * EXTW + (size_t)r * TT + step] = (float)bi_f;
      }
      // logp chunk
      const int j0 = (c < 2) ? c * 1064 : 2128 + (c - 2) * 3000;
      const int jend = (c < 2) ? j0 + 1064 : j0 + 3000;
      float* orow = out + ((size_t)r * TT + step) * EXTW;
      const float* gr = genp + (size_t)r * VV;
      const float* cdr = cdD + (size_t)r * VV;
      const u32* bm = isP + r * 1000;
      for (int j = j0 + tid; j < jend; j += NTHR) {
        float lp;
        if (j < VV) {
          float v = expf(gr[j] - M);
          if ((bm[j >> 5] >> (j & 31)) & 1u) v += expf(cdr[j] - M);
          lp = logf(v / Z + 1e-10f);
        } else lp = LPT;
        __builtin_nontemporal_store(lp, orow + j);
      }
      if (c == 0) {
        __syncthreads();
        float* sw = lds;         // 128
        float* rd = lds + 256;   // 256
        if (tid < SS) {
          int tk = inp[r * SS + tid];
          sw[tid] = (tk == bi_f) ? cssg[r * SS + tid] : 0.f;
        }
        __syncthreads();
        rd[tid] = (tid < SS) ? fabsf(sw[tid]) : 0.f;
        __syncthreads();
        for (int s = 128; s > 0; s >>= 1) { if (tid < s) rd[tid] += rd[tid + s]; __syncthreads(); }
        const float norm = fmaxf(rd[0], 1e-12f);
        __syncthreads();
        if (tid < SS) sw[tid] = sw[tid] / norm;
        __syncthreads();
        for (int h = tid; h < HH; h += NTHR) {
          float a = 0.f;
          for (int s = 0; s < SS; ++s) a += sw[s] * enc[((size_t)r * SS + s) * HH + h];
          rnn[(size_t)r * KX + 512 + h] = a;
        }
        int ic = (bi_f > VV) ? 3 : bi_f;
        if (ic >= VV) ic = VV - 1;
        if (tid < EE) rnn[(size_t)r * KX + 1024 + tid] = embw[(size_t)ic * EE + tid];
      } else if (c == 1) {
        phaseAttn(r, hid, enc, encA, eba, rnn, lds);
      }
    }
    gsync(bar);
  }
}

extern "C" void kernel_launch(void* const* d_in, const int* in_sizes, int n_in,
                              void* d_out, int out_size, void* d_ws, size_t ws_size,
                              hipStream_t stream) {
  const float* enc = (const float*)d_in[0];
  const int* inp = (const int*)d_in[1];
  const float* embw = (const float*)d_in[3];
  const float* attnw = (const float*)d_in[4];
  const float* attnb = (const float*)d_in[5];
  const float* copyw = (const float*)d_in[6];
  const float* copyb = (const float*)d_in[7];
  const float* wih = (const float*)d_in[8];
  const float* whh = (const float*)d_in[9];
  const float* bih = (const float*)d_in[10];
  const float* bhh = (const float*)d_in[11];
  const float* outw = (const float*)d_in[12];
  const float* outb = (const float*)d_in[13];
  (void)in_sizes; (void)n_in; (void)out_size; (void)ws_size;
  hipMemsetAsync(d_ws, 0, 1024, stream);
  copynet<<<dim3(NBLK), dim3(NTHR), 0, stream>>>(
      enc, inp, embw, attnw, attnb, copyw, copyb,
      wih, whh, bih, bhh, outw, outb,
      (float*)d_out, (u32*)d_ws);
}